// Round 3
// baseline (314.471 us; speedup 1.0000x reference)
//
#include <hip/hip_runtime.h>
#include <hip/hip_bf16.h>

typedef __bf16 bf16;
typedef __attribute__((ext_vector_type(4)))  __bf16 bf16x4;
typedef __attribute__((ext_vector_type(8)))  __bf16 bf16x8;
typedef __attribute__((ext_vector_type(16))) float  f32x16;

#define B_   512
#define NC_  512
#define K_   4
#define S_   8
#define H_   128
#define D_   64
#define XROW (NC_ * K_)
#define NITER 16        // 512 items / (4 waves * 8 items/iter)

// pi: swap bits 2,3 of within-32 index (involution). Hidden dims stored
// physically permuted so the 32x32 MFMA C/D register layout of layer k IS
// the B-fragment layout of layer k+1 (r3/r5/r8-verified algebra).
static __device__ __forceinline__ int swap23(int v) {
    return (v & ~12) | ((v & 4) << 1) | ((v & 8) >> 1);
}

// Round-3: barrier-free + spill-free. Each wave owns 32 batch-rows
// end-to-end; zero __syncthreads() in the main loop. Register budget fix
// vs round-1/2 (which spilled ~60 MB of scratch): layer-2 is a single
// pass with all four C accumulators live, consuming each h1 fragment
// immediately after extraction (hfo[8] 32 regs -> 4 transient), and b2 is
// kept as one packed bf16x4 (2 regs) unpacked transiently at the C-init
// rank-1 MFMAs. Acc peak = A(64)+C(64) = 128; arch ~90. Fits 256 unified.
__global__ __launch_bounds__(256, 2)
void jt_mlp_kernel(const int*   __restrict__ x,
                   const float* __restrict__ W1g, const float* __restrict__ b1g,
                   const float* __restrict__ W2g, const float* __restrict__ b2g,
                   const float* __restrict__ W3g, const float* __restrict__ b3g,
                   float* __restrict__ out)
{
    // Swizzled weights: element (row p, k) at p*rowlen + ch*8 + (k&7),
    //   W1: ch = (k>>3) ^ (p&7)
    //   W2: ch = (k>>3) ^ (p&15) ^ ((p&16)>>2)   (5th bit: kills the
    //       l31 vs l31+16 same-bank alias -> 8-access/bank minimum)
    __shared__ __align__(16) bf16 SW2[128 * 128];   // 32 KB
    __shared__ __align__(16) bf16 SWX[128 * 64];    // 16 KB: W1 (persists)
    __shared__ __align__(16) bf16 SW3[8 * 128];     // 2 KB

    const int tid  = threadIdx.x;
    const int lane = tid & 63;
    const int w    = tid >> 6;      // 0..3 (independent waves)
    const int l31  = lane & 31;
    const int lhi  = lane >> 5;
    const int kk   = l31 & 3;
    const int n    = blockIdx.x;    // clique (512 blocks, 2 blocks/CU)

    const float* W1p = W1g + (size_t)n * (D_ * H_);
    const float* W2p = W2g + (size_t)n * (H_ * H_);
    const float* W3p = W3g + (size_t)n * (H_ * S_);
    const float* b1p = b1g + n * H_;
    const float* b2p = b2g + n * H_;
    const float* b3p = b3g + n * S_;

    const int p31 = swap23(l31);
    const bf16 one = (bf16)1.0f, zero = (bf16)0.0f;

    // ============ stage weights into LDS (coalesced float4; r8-proven) ============
    // W1 -> SWX. k<8 rows carry +b1; root n==0 zeroes k<32 first.
    {
        const int c0 = (tid & 31) * 4;
        const int k0 = (tid >> 5) * 8;          // 0..56
        float rows[8][4];
#pragma unroll
        for (int i = 0; i < 8; ++i) {
            float4 t4 = *(const float4*)(W1p + (k0 + i) * H_ + c0);
            if (n == 0 && k0 < 32) t4 = make_float4(0.f, 0.f, 0.f, 0.f);
            rows[i][0] = t4.x; rows[i][1] = t4.y; rows[i][2] = t4.z; rows[i][3] = t4.w;
        }
        if (k0 == 0) {
            const float4 bb = *(const float4*)(b1p + c0);
#pragma unroll
            for (int i = 0; i < 8; ++i) {
                rows[i][0] += bb.x; rows[i][1] += bb.y;
                rows[i][2] += bb.z; rows[i][3] += bb.w;
            }
        }
#pragma unroll
        for (int j2 = 0; j2 < 4; ++j2) {
            const int c = c0 + j2;
            const int p = (c & ~31) | swap23(c & 31);
            const int ch = (k0 >> 3) ^ (p & 7);
            bf16x4 lo, hi;
#pragma unroll
            for (int i = 0; i < 4; ++i) {
                lo[i] = (bf16)rows[i][j2];
                hi[i] = (bf16)rows[4 + i][j2];
            }
            *(bf16x4*)&SWX[p * 64 + ch * 8 + 0] = lo;
            *(bf16x4*)&SWX[p * 64 + ch * 8 + 4] = hi;
        }
    }
    // W2 -> SW2 (5-bit swizzle)
    {
        const int c0 = (tid & 31) * 4;
        const int kbase = (tid >> 5) * 16;      // 0..112
#pragma unroll
        for (int hh = 0; hh < 2; ++hh) {
            const int k0 = kbase + hh * 8;
            float rows[8][4];
#pragma unroll
            for (int i = 0; i < 8; ++i) {
                const float4 t4 = *(const float4*)(W2p + (k0 + i) * H_ + c0);
                rows[i][0] = t4.x; rows[i][1] = t4.y; rows[i][2] = t4.z; rows[i][3] = t4.w;
            }
#pragma unroll
            for (int j2 = 0; j2 < 4; ++j2) {
                const int c = c0 + j2;
                const int p = (c & ~31) | swap23(c & 31);
                const int ch = (k0 >> 3) ^ (p & 15) ^ ((p & 16) >> 2);
                bf16x4 lo, hi;
#pragma unroll
                for (int i = 0; i < 4; ++i) {
                    lo[i] = (bf16)rows[i][j2];
                    hi[i] = (bf16)rows[4 + i][j2];
                }
                *(bf16x4*)&SW2[p * 128 + ch * 8 + 0] = lo;
                *(bf16x4*)&SW2[p * 128 + ch * 8 + 4] = hi;
            }
        }
    }
    // W3^T[s][k] -> SW3
    if (tid < 128) {
        const int s = tid >> 4, kc = tid & 15, k0 = kc * 8;
        float vv[8];
#pragma unroll
        for (int i = 0; i < 8; ++i) vv[i] = W3p[(k0 + i) * S_ + s];
        const int ch = kc ^ s;
        bf16x4 lo, hi;
#pragma unroll
        for (int i = 0; i < 4; ++i) { lo[i] = (bf16)vv[i]; hi[i] = (bf16)vv[4 + i]; }
        *(bf16x4*)&SW3[s * 128 + ch * 8 + 0] = lo;
        *(bf16x4*)&SW3[s * 128 + ch * 8 + 4] = hi;
    }
    __syncthreads();   // the ONLY barrier: staging -> everything else

    const int s2 = l31 & 7;   // lanes 8..31 duplicate state rows (outputs unused)

    // ---- bias: packed b2 (2 regs); onef for the rank-1 bias MFMA ----
    bf16x8 onef;
#pragma unroll
    for (int j = 0; j < 8; ++j) onef[j] = zero;
    onef[0] = lhi ? zero : one;
    bf16x4 w2bp;
#pragma unroll
    for (int aa = 0; aa < 4; ++aa)
        w2bp[aa] = lhi ? zero : (bf16)b2p[32 * aa + p31];
    const float4 b3q = *(const float4*)(b3p + 4 * lhi);

    f32x16 zf;
#pragma unroll
    for (int i = 0; i < 16; ++i) zf[i] = 0.f;

    // -------- x prefetch --------
    const int itbase = w * 8 + (l31 >> 2);
    int4 xo_c, xp_c;
    {
        const int* xb = x + (size_t)itbase * XROW + n * K_;
        xo_c = *(const int4*)xb;
        xp_c = (n > 0) ? *(const int4*)(xb - K_) : make_int4(0, 0, 0, 0);
    }

    const int swz = (l31 & 15) ^ ((l31 & 16) >> 2);
    const int w1x = l31 & 7;
    const int w1r = l31 * 64;
    const int pr0 = (     l31) * 128;
    const int pr1 = (32 + l31) * 128;
    const int pr2 = (64 + l31) * 128;
    const int pr3 = (96 + l31) * 128;

#pragma unroll 1
    for (int c = 0; c < NITER; ++c) {
        const int item = itbase + c * 32;
        const int4 xo = xo_c, xp = xp_c;
        if (c < NITER - 1) {
            const int* xb = x + (size_t)(item + 32) * XROW + n * K_;
            xo_c = *(const int4*)xb;
            xp_c = (n > 0) ? *(const int4*)(xb - K_) : make_int4(0, 0, 0, 0);
        }

        // ---- one-hot selectors (r3/r5-proven) ----
        int sel[4];
        sel[0] = (n > 0) ? (lhi ? xp.y : xp.x) : (lhi ? -1 : 0);
        sel[1] = (n > 0) ? (lhi ? xp.w : xp.z) : -1;
        sel[2] = (kk > (lhi ? 1 : 0)) ? (lhi ? xo.y : xo.x) : -1;
        sel[3] = (kk > (lhi ? 3 : 2)) ? (lhi ? xo.w : xo.z) : -1;

        // ---- layer 1: full H in-wave; W1 frags streamed from LDS ----
        f32x16 A0 = zf, A1 = zf, A2 = zf, A3 = zf;
#pragma unroll
        for (int kt = 0; kt < 4; ++kt) {
            bf16x8 bf1;
#pragma unroll
            for (int j = 0; j < 8; ++j) bf1[j] = (sel[kt] == j) ? one : zero;
            const int ch8 = (((kt << 1) + lhi) ^ w1x) * 8;
            const bf16x8 wf0 = *(const bf16x8*)&SWX[w1r +        ch8];
            const bf16x8 wf1 = *(const bf16x8*)&SWX[w1r + 2048 + ch8];
            const bf16x8 wf2 = *(const bf16x8*)&SWX[w1r + 4096 + ch8];
            const bf16x8 wf3 = *(const bf16x8*)&SWX[w1r + 6144 + ch8];
            A0 = __builtin_amdgcn_mfma_f32_32x32x16_bf16(wf0, bf1, A0, 0, 0, 0);
            A1 = __builtin_amdgcn_mfma_f32_32x32x16_bf16(wf1, bf1, A1, 0, 0, 0);
            A2 = __builtin_amdgcn_mfma_f32_32x32x16_bf16(wf2, bf1, A2, 0, 0, 0);
            A3 = __builtin_amdgcn_mfma_f32_32x32x16_bf16(wf3, bf1, A3, 0, 0, 0);
        }

        // ---- layer 2: single pass, extract-and-consume (no hfo[8]) ----
        // C init via rank-1 bias MFMA (b2 unpacked transiently from w2bp).
        f32x16 C0, C1, C2, C3;
        {
            bf16x8 wb;
#pragma unroll
            for (int j = 0; j < 8; ++j) wb[j] = zero;
            wb[0] = w2bp[0];
            C0 = __builtin_amdgcn_mfma_f32_32x32x16_bf16(wb, onef, zf, 0, 0, 0);
            wb[0] = w2bp[1];
            C1 = __builtin_amdgcn_mfma_f32_32x32x16_bf16(wb, onef, zf, 0, 0, 0);
            wb[0] = w2bp[2];
            C2 = __builtin_amdgcn_mfma_f32_32x32x16_bf16(wb, onef, zf, 0, 0, 0);
            wb[0] = w2bp[3];
            C3 = __builtin_amdgcn_mfma_f32_32x32x16_bf16(wb, onef, zf, 0, 0, 0);
        }
#pragma unroll
        for (int t = 0; t < 8; ++t) {
            const f32x16& Sa = (t < 2) ? A0 : (t < 4) ? A1 : (t < 6) ? A2 : A3;
            bf16x8 hf;
#pragma unroll
            for (int j = 0; j < 8; ++j)
                hf[j] = (bf16)fmaxf(Sa[8 * (t & 1) + j], 0.f);
            const int chunk = ((t << 1) + lhi) ^ swz;
            const bf16x8 f0 = *(const bf16x8*)&SW2[pr0 + chunk * 8];
            const bf16x8 f1 = *(const bf16x8*)&SW2[pr1 + chunk * 8];
            const bf16x8 f2 = *(const bf16x8*)&SW2[pr2 + chunk * 8];
            const bf16x8 f3 = *(const bf16x8*)&SW2[pr3 + chunk * 8];
            C0 = __builtin_amdgcn_mfma_f32_32x32x16_bf16(f0, hf, C0, 0, 0, 0);
            C1 = __builtin_amdgcn_mfma_f32_32x32x16_bf16(f1, hf, C1, 0, 0, 0);
            C2 = __builtin_amdgcn_mfma_f32_32x32x16_bf16(f2, hf, C2, 0, 0, 0);
            C3 = __builtin_amdgcn_mfma_f32_32x32x16_bf16(f3, hf, C3, 0, 0, 0);
        }

        // ---- layer 3: extract-and-consume from C (A dead; L reuses space) ----
        f32x16 L = zf;
#pragma unroll
        for (int q = 0; q < 8; ++q) {
            const f32x16& Sc = (q < 2) ? C0 : (q < 4) ? C1 : (q < 6) ? C2 : C3;
            bf16x8 hg;
#pragma unroll
            for (int j = 0; j < 8; ++j)
                hg[j] = (bf16)fmaxf(Sc[8 * (q & 1) + j], 0.f);
            const bf16x8 w3q = *(const bf16x8*)
                &SW3[s2 * 128 + (((q << 1) + lhi) ^ s2) * 8];
            L = __builtin_amdgcn_mfma_f32_32x32x16_bf16(w3q, hg, L, 0, 0, 0);
        }

        // ---- epilogue: fully in-wave (full K accumulated) ----
        {
            const float Ls0 = L[0] + b3q.x;
            const float Ls1 = L[1] + b3q.y;
            const float Ls2 = L[2] + b3q.z;
            const float Ls3 = L[3] + b3q.w;

            float m4 = fmaxf(fmaxf(Ls0, Ls1), fmaxf(Ls2, Ls3));
            const float mm = fmaxf(m4, __shfl_xor(m4, 32));
            float e = __expf(Ls0 - mm) + __expf(Ls1 - mm) +
                      __expf(Ls2 - mm) + __expf(Ls3 - mm);
            const float ssum = e + __shfl_xor(e, 32);

            const int xs = (kk & 2) ? ((kk & 1) ? xo.w : xo.z)
                                    : ((kk & 1) ? xo.y : xo.x);
            const float own = (xs & 2) ? ((xs & 1) ? Ls3 : Ls2)
                                       : ((xs & 1) ? Ls1 : Ls0);
            const float oth = __shfl_xor(own, 32);
            const float obs = ((xs >> 2) == lhi) ? own : oth;
            float lp = obs - mm - __logf(ssum);
            lp += __shfl_xor(lp, 1);
            lp += __shfl_xor(lp, 2);
            if (lhi == 0 && kk == 0)
                out[(size_t)item * NC_ + n] = lp;
        }
    }
}

extern "C" void kernel_launch(void* const* d_in, const int* in_sizes, int n_in,
                              void* d_out, int out_size, void* d_ws, size_t ws_size,
                              hipStream_t stream) {
    const int*   x  = (const int*)d_in[0];
    const float* W1 = (const float*)d_in[1];
    const float* b1 = (const float*)d_in[2];
    const float* W2 = (const float*)d_in[3];
    const float* b2 = (const float*)d_in[4];
    const float* W3 = (const float*)d_in[5];
    const float* b3 = (const float*)d_in[6];
    float* out = (float*)d_out;
    jt_mlp_kernel<<<dim3(NC_), 256, 0, stream>>>(x, W1, b1, W2, b2, W3, b3, out);
}

// Round 4
// 267.764 us; speedup vs baseline: 1.1744x; 1.1744x over previous
//
#include <hip/hip_runtime.h>
#include <hip/hip_bf16.h>

typedef __bf16 bf16;
typedef __attribute__((ext_vector_type(4)))  __bf16 bf16x4;
typedef __attribute__((ext_vector_type(8)))  __bf16 bf16x8;
typedef __attribute__((ext_vector_type(16))) float  f32x16;

#define B_   512
#define NC_  512
#define K_   4
#define S_   8
#define H_   128
#define D_   64
#define XROW (NC_ * K_)
#define NITER 16        // 512 items / (4 waves * 8 items/iter)

// pi: swap bits 2,3 of within-32 index (involution). Hidden dims stored
// physically permuted so the 32x32 MFMA C/D register layout of layer k IS
// the B-fragment layout of layer k+1 (r3/r5/r8-verified algebra).
static __device__ __forceinline__ int swap23(int v) {
    return (v & ~12) | ((v & 4) << 1) | ((v & 8) >> 1);
}

// Round-4: barrier-free + acc-pressure fix. Rounds 1-3 spilled because the
// layer1->layer2 boundary held A0..A3 + C0..C3 = 128 acc regs (the whole
// acc half at 2 waves/SIMD). Fix: fuse layers 1 and 2 per 32-row H-group --
// compute ONE A accumulator, immediately consume its two h1 fragments into
// C0..C3, then reuse A for the next group. Acc peak: A(16)+C(64) = 80;
// layer-3 phase C(64)+L(16) = 80. Arch ~100. Both fit 128/128 with slack.
__global__ __launch_bounds__(256, 2)
void jt_mlp_kernel(const int*   __restrict__ x,
                   const float* __restrict__ W1g, const float* __restrict__ b1g,
                   const float* __restrict__ W2g, const float* __restrict__ b2g,
                   const float* __restrict__ W3g, const float* __restrict__ b3g,
                   float* __restrict__ out)
{
    // Swizzled weights: element (row p, k) at p*rowlen + ch*8 + (k&7),
    //   W1: ch = (k>>3) ^ (p&7)
    //   W2: ch = (k>>3) ^ (p&15) ^ ((p&16)>>2)   (5th bit: kills the
    //       l31 vs l31+16 same-bank alias -> 8-access/bank minimum)
    __shared__ __align__(16) bf16 SW2[128 * 128];   // 32 KB
    __shared__ __align__(16) bf16 SWX[128 * 64];    // 16 KB: W1 (persists)
    __shared__ __align__(16) bf16 SW3[8 * 128];     // 2 KB

    const int tid  = threadIdx.x;
    const int lane = tid & 63;
    const int w    = tid >> 6;      // 0..3 (independent waves)
    const int l31  = lane & 31;
    const int lhi  = lane >> 5;
    const int kk   = l31 & 3;
    const int n    = blockIdx.x;    // clique (512 blocks, 2 blocks/CU)

    const float* W1p = W1g + (size_t)n * (D_ * H_);
    const float* W2p = W2g + (size_t)n * (H_ * H_);
    const float* W3p = W3g + (size_t)n * (H_ * S_);
    const float* b1p = b1g + n * H_;
    const float* b2p = b2g + n * H_;
    const float* b3p = b3g + n * S_;

    const int p31 = swap23(l31);
    const bf16 one = (bf16)1.0f, zero = (bf16)0.0f;

    // ============ stage weights into LDS (coalesced float4; r8-proven) ============
    // W1 -> SWX. k<8 rows carry +b1; root n==0 zeroes k<32 first.
    {
        const int c0 = (tid & 31) * 4;
        const int k0 = (tid >> 5) * 8;          // 0..56
        float rows[8][4];
#pragma unroll
        for (int i = 0; i < 8; ++i) {
            float4 t4 = *(const float4*)(W1p + (k0 + i) * H_ + c0);
            if (n == 0 && k0 < 32) t4 = make_float4(0.f, 0.f, 0.f, 0.f);
            rows[i][0] = t4.x; rows[i][1] = t4.y; rows[i][2] = t4.z; rows[i][3] = t4.w;
        }
        if (k0 == 0) {
            const float4 bb = *(const float4*)(b1p + c0);
#pragma unroll
            for (int i = 0; i < 8; ++i) {
                rows[i][0] += bb.x; rows[i][1] += bb.y;
                rows[i][2] += bb.z; rows[i][3] += bb.w;
            }
        }
#pragma unroll
        for (int j2 = 0; j2 < 4; ++j2) {
            const int c = c0 + j2;
            const int p = (c & ~31) | swap23(c & 31);
            const int ch = (k0 >> 3) ^ (p & 7);
            bf16x4 lo, hi;
#pragma unroll
            for (int i = 0; i < 4; ++i) {
                lo[i] = (bf16)rows[i][j2];
                hi[i] = (bf16)rows[4 + i][j2];
            }
            *(bf16x4*)&SWX[p * 64 + ch * 8 + 0] = lo;
            *(bf16x4*)&SWX[p * 64 + ch * 8 + 4] = hi;
        }
    }
    // W2 -> SW2 (5-bit swizzle)
    {
        const int c0 = (tid & 31) * 4;
        const int kbase = (tid >> 5) * 16;      // 0..112
#pragma unroll
        for (int hh = 0; hh < 2; ++hh) {
            const int k0 = kbase + hh * 8;
            float rows[8][4];
#pragma unroll
            for (int i = 0; i < 8; ++i) {
                const float4 t4 = *(const float4*)(W2p + (k0 + i) * H_ + c0);
                rows[i][0] = t4.x; rows[i][1] = t4.y; rows[i][2] = t4.z; rows[i][3] = t4.w;
            }
#pragma unroll
            for (int j2 = 0; j2 < 4; ++j2) {
                const int c = c0 + j2;
                const int p = (c & ~31) | swap23(c & 31);
                const int ch = (k0 >> 3) ^ (p & 15) ^ ((p & 16) >> 2);
                bf16x4 lo, hi;
#pragma unroll
                for (int i = 0; i < 4; ++i) {
                    lo[i] = (bf16)rows[i][j2];
                    hi[i] = (bf16)rows[4 + i][j2];
                }
                *(bf16x4*)&SW2[p * 128 + ch * 8 + 0] = lo;
                *(bf16x4*)&SW2[p * 128 + ch * 8 + 4] = hi;
            }
        }
    }
    // W3^T[s][k] -> SW3
    if (tid < 128) {
        const int s = tid >> 4, kc = tid & 15, k0 = kc * 8;
        float vv[8];
#pragma unroll
        for (int i = 0; i < 8; ++i) vv[i] = W3p[(k0 + i) * S_ + s];
        const int ch = kc ^ s;
        bf16x4 lo, hi;
#pragma unroll
        for (int i = 0; i < 4; ++i) { lo[i] = (bf16)vv[i]; hi[i] = (bf16)vv[4 + i]; }
        *(bf16x4*)&SW3[s * 128 + ch * 8 + 0] = lo;
        *(bf16x4*)&SW3[s * 128 + ch * 8 + 4] = hi;
    }
    __syncthreads();   // the ONLY barrier: staging -> everything else

    const int s2 = l31 & 7;   // lanes 8..31 duplicate state rows (outputs unused)

    // ---- bias: packed b2 (2 regs); onef for the rank-1 bias MFMA ----
    bf16x8 onef;
#pragma unroll
    for (int j = 0; j < 8; ++j) onef[j] = zero;
    onef[0] = lhi ? zero : one;
    bf16x4 w2bp;
#pragma unroll
    for (int aa = 0; aa < 4; ++aa)
        w2bp[aa] = lhi ? zero : (bf16)b2p[32 * aa + p31];
    const float4 b3q = *(const float4*)(b3p + 4 * lhi);

    f32x16 zf;
#pragma unroll
    for (int i = 0; i < 16; ++i) zf[i] = 0.f;

    // -------- x prefetch --------
    const int itbase = w * 8 + (l31 >> 2);
    int4 xo_c, xp_c;
    {
        const int* xb = x + (size_t)itbase * XROW + n * K_;
        xo_c = *(const int4*)xb;
        xp_c = (n > 0) ? *(const int4*)(xb - K_) : make_int4(0, 0, 0, 0);
    }

    const int swz = (l31 & 15) ^ ((l31 & 16) >> 2);
    const int w1x = l31 & 7;
    const int w1r = l31 * 64;
    const int pr0 = (     l31) * 128;
    const int pr1 = (32 + l31) * 128;
    const int pr2 = (64 + l31) * 128;
    const int pr3 = (96 + l31) * 128;

#pragma unroll 1
    for (int c = 0; c < NITER; ++c) {
        const int item = itbase + c * 32;
        const int4 xo = xo_c, xp = xp_c;
        if (c < NITER - 1) {
            const int* xb = x + (size_t)(item + 32) * XROW + n * K_;
            xo_c = *(const int4*)xb;
            xp_c = (n > 0) ? *(const int4*)(xb - K_) : make_int4(0, 0, 0, 0);
        }

        // ---- one-hot selectors (r3/r5-proven) ----
        int sel[4];
        sel[0] = (n > 0) ? (lhi ? xp.y : xp.x) : (lhi ? -1 : 0);
        sel[1] = (n > 0) ? (lhi ? xp.w : xp.z) : -1;
        sel[2] = (kk > (lhi ? 1 : 0)) ? (lhi ? xo.y : xo.x) : -1;
        sel[3] = (kk > (lhi ? 3 : 2)) ? (lhi ? xo.w : xo.z) : -1;

        // ---- one-hot B-frags, hoisted once per iter (16 arch regs) ----
        bf16x8 bf1f[4];
#pragma unroll
        for (int kt = 0; kt < 4; ++kt)
#pragma unroll
            for (int j = 0; j < 8; ++j)
                bf1f[kt][j] = (sel[kt] == j) ? one : zero;

        // ---- C init via rank-1 bias MFMA (b2 unpacked transiently) ----
        f32x16 C0, C1, C2, C3;
        {
            bf16x8 wb;
#pragma unroll
            for (int j = 0; j < 8; ++j) wb[j] = zero;
            wb[0] = w2bp[0];
            C0 = __builtin_amdgcn_mfma_f32_32x32x16_bf16(wb, onef, zf, 0, 0, 0);
            wb[0] = w2bp[1];
            C1 = __builtin_amdgcn_mfma_f32_32x32x16_bf16(wb, onef, zf, 0, 0, 0);
            wb[0] = w2bp[2];
            C2 = __builtin_amdgcn_mfma_f32_32x32x16_bf16(wb, onef, zf, 0, 0, 0);
            wb[0] = w2bp[3];
            C3 = __builtin_amdgcn_mfma_f32_32x32x16_bf16(wb, onef, zf, 0, 0, 0);
        }

        // ---- fused layer 1+2: one A group at a time (acc peak 16+64) ----
#pragma unroll
        for (int aa = 0; aa < 4; ++aa) {
            f32x16 A = zf;
#pragma unroll
            for (int kt = 0; kt < 4; ++kt) {
                const bf16x8 wf = *(const bf16x8*)
                    &SWX[w1r + aa * 2048 + ((((kt << 1) + lhi) ^ w1x) * 8)];
                A = __builtin_amdgcn_mfma_f32_32x32x16_bf16(wf, bf1f[kt], A, 0, 0, 0);
            }
#pragma unroll
            for (int e = 0; e < 2; ++e) {
                const int t = 2 * aa + e;
                bf16x8 hf;
#pragma unroll
                for (int j = 0; j < 8; ++j)
                    hf[j] = (bf16)fmaxf(A[8 * e + j], 0.f);
                const int chunk = ((t << 1) + lhi) ^ swz;
                const bf16x8 f0 = *(const bf16x8*)&SW2[pr0 + chunk * 8];
                const bf16x8 f1 = *(const bf16x8*)&SW2[pr1 + chunk * 8];
                const bf16x8 f2 = *(const bf16x8*)&SW2[pr2 + chunk * 8];
                const bf16x8 f3 = *(const bf16x8*)&SW2[pr3 + chunk * 8];
                C0 = __builtin_amdgcn_mfma_f32_32x32x16_bf16(f0, hf, C0, 0, 0, 0);
                C1 = __builtin_amdgcn_mfma_f32_32x32x16_bf16(f1, hf, C1, 0, 0, 0);
                C2 = __builtin_amdgcn_mfma_f32_32x32x16_bf16(f2, hf, C2, 0, 0, 0);
                C3 = __builtin_amdgcn_mfma_f32_32x32x16_bf16(f3, hf, C3, 0, 0, 0);
            }
        }

        // ---- layer 3: extract-and-consume from C (acc peak 64+16) ----
        f32x16 L = zf;
#pragma unroll
        for (int q = 0; q < 8; ++q) {
            const f32x16& Sc = (q < 2) ? C0 : (q < 4) ? C1 : (q < 6) ? C2 : C3;
            bf16x8 hg;
#pragma unroll
            for (int j = 0; j < 8; ++j)
                hg[j] = (bf16)fmaxf(Sc[8 * (q & 1) + j], 0.f);
            const bf16x8 w3q = *(const bf16x8*)
                &SW3[s2 * 128 + (((q << 1) + lhi) ^ s2) * 8];
            L = __builtin_amdgcn_mfma_f32_32x32x16_bf16(w3q, hg, L, 0, 0, 0);
        }

        // ---- epilogue: fully in-wave (full K accumulated) ----
        {
            const float Ls0 = L[0] + b3q.x;
            const float Ls1 = L[1] + b3q.y;
            const float Ls2 = L[2] + b3q.z;
            const float Ls3 = L[3] + b3q.w;

            float m4 = fmaxf(fmaxf(Ls0, Ls1), fmaxf(Ls2, Ls3));
            const float mm = fmaxf(m4, __shfl_xor(m4, 32));
            float e = __expf(Ls0 - mm) + __expf(Ls1 - mm) +
                      __expf(Ls2 - mm) + __expf(Ls3 - mm);
            const float ssum = e + __shfl_xor(e, 32);

            const int xs = (kk & 2) ? ((kk & 1) ? xo.w : xo.z)
                                    : ((kk & 1) ? xo.y : xo.x);
            const float own = (xs & 2) ? ((xs & 1) ? Ls3 : Ls2)
                                       : ((xs & 1) ? Ls1 : Ls0);
            const float oth = __shfl_xor(own, 32);
            const float obs = ((xs >> 2) == lhi) ? own : oth;
            float lp = obs - mm - __logf(ssum);
            lp += __shfl_xor(lp, 1);
            lp += __shfl_xor(lp, 2);
            if (lhi == 0 && kk == 0)
                out[(size_t)item * NC_ + n] = lp;
        }
    }
}

extern "C" void kernel_launch(void* const* d_in, const int* in_sizes, int n_in,
                              void* d_out, int out_size, void* d_ws, size_t ws_size,
                              hipStream_t stream) {
    const int*   x  = (const int*)d_in[0];
    const float* W1 = (const float*)d_in[1];
    const float* b1 = (const float*)d_in[2];
    const float* W2 = (const float*)d_in[3];
    const float* b2 = (const float*)d_in[4];
    const float* W3 = (const float*)d_in[5];
    const float* b3 = (const float*)d_in[6];
    float* out = (float*)d_out;
    jt_mlp_kernel<<<dim3(NC_), 256, 0, stream>>>(x, W1, b1, W2, b2, W3, b3, out);
}

// Round 5
// 167.910 us; speedup vs baseline: 1.8729x; 1.5947x over previous
//
#include <hip/hip_runtime.h>
#include <hip/hip_bf16.h>

typedef __bf16 bf16;
typedef __attribute__((ext_vector_type(4)))  __bf16 bf16x4;
typedef __attribute__((ext_vector_type(8)))  __bf16 bf16x8;
typedef __attribute__((ext_vector_type(16))) float  f32x16;

#define B_   512
#define NC_  512
#define K_   4
#define S_   8
#define H_   128
#define D_   64
#define XROW (NC_ * K_)
#define SEGS 2
#define NITER 16        // 256 items per block / (2 pairs * 8 items/iter)

// pi: swap bits 2,3 of within-32 index (involution). Hidden dims stored
// physically permuted so the 32x32 MFMA C/D register layout of layer k IS
// the B-fragment layout of layer k+1 (r3/r5/r8-verified algebra).
static __device__ __forceinline__ int swap23(int v) {
    return (v & ~12) | ((v & 4) << 1) | ((v & 8) >> 1);
}

// Round-5: REVERT to the round-0 pair-split structure (76 VGPR, zero spill;
// rounds 1-4's wave-independent restructure always spilled: VGPR pinned at
// 128 + 60-80 MB scratch writes). New lever: occupancy. Round-0 was
// latency/barrier-bound at 2 blocks/CU (20% occ) while LDS (52 KB) and regs
// allow 3 blocks/CU. SEGS=2 splits the batch -> grid 1024, NITER 16 ->
// 3 resident blocks/CU (12 waves) hide barrier/dep stalls. blockIdx =
// seg*512 + n keeps both segments of clique n on the SAME XCD (512%8==0),
// so the duplicated weight read hits L2.
__global__ __launch_bounds__(256, 2)
void jt_mlp_kernel(const int*   __restrict__ x,
                   const float* __restrict__ W1g, const float* __restrict__ b1g,
                   const float* __restrict__ W2g, const float* __restrict__ b2g,
                   const float* __restrict__ W3g, const float* __restrict__ b3g,
                   float* __restrict__ out)
{
    // Swizzled weights: element (row p, k) at p*rowlen + ch*8 + (k&7),
    //   W1: ch = (k>>3) ^ (p&7)
    //   W2: ch = (k>>3) ^ (p&15) ^ ((p&16)>>2)   (5th bit: kills the
    //       l31 vs l31+16 same-bank alias -> 8-access/bank minimum)
    __shared__ __align__(16) bf16 SW2[128 * 128];   // 32 KB
    __shared__ __align__(16) bf16 SWX[128 * 64];    // 16 KB: W1 staging, then HX
    __shared__ __align__(16) bf16 SW3[8 * 128];     // 2 KB
    __shared__ __align__(16) float LX[2][64][4];    // 2 KB (h=1 writes, h=0 reads)

    const int tid  = threadIdx.x;
    const int lane = tid & 63;
    const int w    = tid >> 6;      // 0..3
    const int pair = w >> 1;        // 0,1
    const int h    = w & 1;         // H-half owned by this wave
    const int l31  = lane & 31;
    const int lhi  = lane >> 5;
    const int kk   = l31 & 3;
    const int bid  = blockIdx.x;    // seg*512 + n (same-XCD pairing)
    const int n    = bid & (NC_ - 1);
    const int seg  = bid >> 9;

    const float* W1p = W1g + (size_t)n * (D_ * H_);
    const float* W2p = W2g + (size_t)n * (H_ * H_);
    const float* W3p = W3g + (size_t)n * (H_ * S_);
    const float* b1p = b1g + n * H_;
    const float* b2p = b2g + n * H_;
    const float* b3p = b3g + n * S_;

    const int p31 = swap23(l31);
    const bf16 one = (bf16)1.0f, zero = (bf16)0.0f;

    // ============ stage weights into LDS (coalesced float4; r8-proven) ============
    // W1 -> SWX (temporarily). k<8 rows carry +b1; root n==0 zeroes k<32 first.
    {
        const int c0 = (tid & 31) * 4;
        const int k0 = (tid >> 5) * 8;          // 0..56
        float rows[8][4];
#pragma unroll
        for (int i = 0; i < 8; ++i) {
            float4 t4 = *(const float4*)(W1p + (k0 + i) * H_ + c0);
            if (n == 0 && k0 < 32) t4 = make_float4(0.f, 0.f, 0.f, 0.f);
            rows[i][0] = t4.x; rows[i][1] = t4.y; rows[i][2] = t4.z; rows[i][3] = t4.w;
        }
        if (k0 == 0) {
            const float4 bb = *(const float4*)(b1p + c0);
#pragma unroll
            for (int i = 0; i < 8; ++i) {
                rows[i][0] += bb.x; rows[i][1] += bb.y;
                rows[i][2] += bb.z; rows[i][3] += bb.w;
            }
        }
#pragma unroll
        for (int j2 = 0; j2 < 4; ++j2) {
            const int c = c0 + j2;
            const int p = (c & ~31) | swap23(c & 31);
            const int ch = (k0 >> 3) ^ (p & 7);
            bf16x4 lo, hi;
#pragma unroll
            for (int i = 0; i < 4; ++i) {
                lo[i] = (bf16)rows[i][j2];
                hi[i] = (bf16)rows[4 + i][j2];
            }
            *(bf16x4*)&SWX[p * 64 + ch * 8 + 0] = lo;
            *(bf16x4*)&SWX[p * 64 + ch * 8 + 4] = hi;
        }
    }
    // W2 -> SW2 (5-bit swizzle)
    {
        const int c0 = (tid & 31) * 4;
        const int kbase = (tid >> 5) * 16;      // 0..112
#pragma unroll
        for (int hh = 0; hh < 2; ++hh) {
            const int k0 = kbase + hh * 8;
            float rows[8][4];
#pragma unroll
            for (int i = 0; i < 8; ++i) {
                const float4 t4 = *(const float4*)(W2p + (k0 + i) * H_ + c0);
                rows[i][0] = t4.x; rows[i][1] = t4.y; rows[i][2] = t4.z; rows[i][3] = t4.w;
            }
#pragma unroll
            for (int j2 = 0; j2 < 4; ++j2) {
                const int c = c0 + j2;
                const int p = (c & ~31) | swap23(c & 31);
                const int ch = (k0 >> 3) ^ (p & 15) ^ ((p & 16) >> 2);
                bf16x4 lo, hi;
#pragma unroll
                for (int i = 0; i < 4; ++i) {
                    lo[i] = (bf16)rows[i][j2];
                    hi[i] = (bf16)rows[4 + i][j2];
                }
                *(bf16x4*)&SW2[p * 128 + ch * 8 + 0] = lo;
                *(bf16x4*)&SW2[p * 128 + ch * 8 + 4] = hi;
            }
        }
    }
    // W3^T[s][k] -> SW3
    if (tid < 128) {
        const int s = tid >> 4, kc = tid & 15, k0 = kc * 8;
        float vv[8];
#pragma unroll
        for (int i = 0; i < 8; ++i) vv[i] = W3p[(k0 + i) * S_ + s];
        const int ch = kc ^ s;
        bf16x4 lo, hi;
#pragma unroll
        for (int i = 0; i < 4; ++i) { lo[i] = (bf16)vv[i]; hi[i] = (bf16)vv[4 + i]; }
        *(bf16x4*)&SW3[s * 128 + ch * 8 + 0] = lo;
        *(bf16x4*)&SW3[s * 128 + ch * 8 + 4] = hi;
    }
    __syncthreads();

    // ---- W1 fragments for this wave's H-half: registers, from LDS ----
    bf16x8 w1f[2][4];
#pragma unroll
    for (int aa = 0; aa < 2; ++aa)
#pragma unroll
        for (int kt = 0; kt < 4; ++kt)
            w1f[aa][kt] = *(const bf16x8*)
                &SWX[(32 * (2 * h + aa) + l31) * 64 + (((kt << 1) + lhi) ^ (l31 & 7)) * 8];
    // ---- W3 fragments (this wave's k-half: kglobal = 64h+16tt+8lhi+j) ----
    const int s2 = l31 & 7;   // lanes 8..31 duplicate state rows (outputs unused)
    bf16x8 w3f[4];
#pragma unroll
    for (int tt = 0; tt < 4; ++tt)
        w3f[tt] = *(const bf16x8*)
            &SW3[s2 * 128 + ((((4 * h + tt) << 1) + lhi) ^ s2) * 8];
    // ---- bias frags ----
    bf16x8 w2b0, w2b1, onef;
#pragma unroll
    for (int j = 0; j < 8; ++j) { w2b0[j] = zero; w2b1[j] = zero; onef[j] = zero; }
    w2b0[0] = lhi ? zero : (bf16)b2p[32 * (2 * h + 0) + p31];
    w2b1[0] = lhi ? zero : (bf16)b2p[32 * (2 * h + 1) + p31];
    onef[0] = lhi ? zero : one;
    const float4 b3q = *(const float4*)(b3p + 4 * lhi);

    f32x16 zf;
#pragma unroll
    for (int i = 0; i < 16; ++i) zf[i] = 0.f;

    __syncthreads();   // w1f reads done -> SWX becomes the HX exchange buffer
    bf16* HX = SWX;    // HX[pair][half][t][lane][8] = ((pair*2+half)*4+t)*512 + lane*8

    // -------- x prefetch --------
    const int itbase = seg * 256 + pair * 128 + (l31 >> 2);
    int4 xo_c, xp_c;
    {
        const int* xb = x + (size_t)itbase * XROW + n * K_;
        xo_c = *(const int4*)xb;
        xp_c = (n > 0) ? *(const int4*)(xb - K_) : make_int4(0, 0, 0, 0);
    }

#pragma unroll 1
    for (int c = 0; c < NITER; ++c) {
        const int item = itbase + c * 8;
        const int4 xo = xo_c, xp = xp_c;
        if (c < NITER - 1) {
            const int* xb = x + (size_t)(item + 8) * XROW + n * K_;
            xo_c = *(const int4*)xb;
            xp_c = (n > 0) ? *(const int4*)(xb - K_) : make_int4(0, 0, 0, 0);
        }

        // ---- one-hot selectors (r3/r5-proven) ----
        int sel[4];
        sel[0] = (n > 0) ? (lhi ? xp.y : xp.x) : (lhi ? -1 : 0);
        sel[1] = (n > 0) ? (lhi ? xp.w : xp.z) : -1;
        sel[2] = (kk > (lhi ? 1 : 0)) ? (lhi ? xo.y : xo.x) : -1;
        sel[3] = (kk > (lhi ? 3 : 2)) ? (lhi ? xo.w : xo.z) : -1;

        // ---- layer 1 (own H-half; one-hot B-frag built per kt) ----
        f32x16 A0 = zf, A1 = zf;
#pragma unroll
        for (int kt = 0; kt < 4; ++kt) {
            bf16x8 bf1;
#pragma unroll
            for (int j = 0; j < 8; ++j) bf1[j] = (sel[kt] == j) ? one : zero;
            A0 = __builtin_amdgcn_mfma_f32_32x32x16_bf16(w1f[0][kt], bf1, A0, 0, 0, 0);
            A1 = __builtin_amdgcn_mfma_f32_32x32x16_bf16(w1f[1][kt], bf1, A1, 0, 0, 0);
        }

        // ---- extract own h1 frags (chained layout), publish to partner ----
        bf16x8 hfo[4];
#pragma unroll
        for (int t = 0; t < 4; ++t) {
            const f32x16& S = (t < 2) ? A0 : A1;
#pragma unroll
            for (int j = 0; j < 8; ++j)
                hfo[t][j] = (bf16)fmaxf(S[8 * (t & 1) + j], 0.f);
            *(bf16x8*)&HX[(((pair << 1) + h) * 4 + t) * 512 + lane * 8] = hfo[t];
        }
        __syncthreads();

        // ---- layer 2: W2 frags streamed from LDS; own kt then partner kt ----
        f32x16 C0 = zf, C1 = zf;
        const int swz = (l31 & 15) ^ ((l31 & 16) >> 2);
        const int p0 = (64 * h + l31) * 128;
        const int p1 = (64 * h + 32 + l31) * 128;
#pragma unroll
        for (int tt = 0; tt < 4; ++tt) {
            const int chunk = (((4 * h + tt) << 1) + lhi) ^ swz;
            const bf16x8 f0 = *(const bf16x8*)&SW2[p0 + chunk * 8];
            const bf16x8 f1 = *(const bf16x8*)&SW2[p1 + chunk * 8];
            C0 = __builtin_amdgcn_mfma_f32_32x32x16_bf16(f0, hfo[tt], C0, 0, 0, 0);
            C1 = __builtin_amdgcn_mfma_f32_32x32x16_bf16(f1, hfo[tt], C1, 0, 0, 0);
        }
#pragma unroll
        for (int tt = 0; tt < 4; ++tt) {
            const bf16x8 hp = *(const bf16x8*)
                &HX[(((pair << 1) + (1 - h)) * 4 + tt) * 512 + lane * 8];
            const int chunk = (((4 * (1 - h) + tt) << 1) + lhi) ^ swz;
            const bf16x8 f0 = *(const bf16x8*)&SW2[p0 + chunk * 8];
            const bf16x8 f1 = *(const bf16x8*)&SW2[p1 + chunk * 8];
            C0 = __builtin_amdgcn_mfma_f32_32x32x16_bf16(f0, hp, C0, 0, 0, 0);
            C1 = __builtin_amdgcn_mfma_f32_32x32x16_bf16(f1, hp, C1, 0, 0, 0);
        }
        C0 = __builtin_amdgcn_mfma_f32_32x32x16_bf16(w2b0, onef, C0, 0, 0, 0);
        C1 = __builtin_amdgcn_mfma_f32_32x32x16_bf16(w2b1, onef, C1, 0, 0, 0);

        // ---- layer 3 partial over own k-half ----
        f32x16 L = zf;
#pragma unroll
        for (int tt = 0; tt < 4; ++tt) {
            bf16x8 hg;
            const f32x16& S = (tt < 2) ? C0 : C1;
#pragma unroll
            for (int j = 0; j < 8; ++j)
                hg[j] = (bf16)fmaxf(S[8 * (tt & 1) + j], 0.f);
            L = __builtin_amdgcn_mfma_f32_32x32x16_bf16(w3f[tt], hg, L, 0, 0, 0);
        }

        // ---- sum partials across the pair; epilogue on h==0 (r5-proven) ----
        if (h == 1)
            *(float4*)&LX[pair][lane][0] = make_float4(L[0], L[1], L[2], L[3]);
        __syncthreads();
        if (h == 0) {
            const float4 Lp = *(const float4*)&LX[pair][lane][0];
            float Ls0 = L[0] + Lp.x + b3q.x;
            float Ls1 = L[1] + Lp.y + b3q.y;
            float Ls2 = L[2] + Lp.z + b3q.z;
            float Ls3 = L[3] + Lp.w + b3q.w;

            float m4 = fmaxf(fmaxf(Ls0, Ls1), fmaxf(Ls2, Ls3));
            const float mm = fmaxf(m4, __shfl_xor(m4, 32));
            float e = __expf(Ls0 - mm) + __expf(Ls1 - mm) +
                      __expf(Ls2 - mm) + __expf(Ls3 - mm);
            const float ssum = e + __shfl_xor(e, 32);

            const int xs = (kk & 2) ? ((kk & 1) ? xo.w : xo.z)
                                    : ((kk & 1) ? xo.y : xo.x);
            const float own = (xs & 2) ? ((xs & 1) ? Ls3 : Ls2)
                                       : ((xs & 1) ? Ls1 : Ls0);
            const float oth = __shfl_xor(own, 32);
            const float obs = ((xs >> 2) == lhi) ? own : oth;
            float lp = obs - mm - __logf(ssum);
            lp += __shfl_xor(lp, 1);
            lp += __shfl_xor(lp, 2);
            if (lhi == 0 && kk == 0)
                out[(size_t)item * NC_ + n] = lp;
        }
        // HX overwrite next iter is safe: all HX reads completed before the
        // second barrier; LX read (h==0) completes before next first barrier.
    }
}

extern "C" void kernel_launch(void* const* d_in, const int* in_sizes, int n_in,
                              void* d_out, int out_size, void* d_ws, size_t ws_size,
                              hipStream_t stream) {
    const int*   x  = (const int*)d_in[0];
    const float* W1 = (const float*)d_in[1];
    const float* b1 = (const float*)d_in[2];
    const float* W2 = (const float*)d_in[3];
    const float* b2 = (const float*)d_in[4];
    const float* W3 = (const float*)d_in[5];
    const float* b3 = (const float*)d_in[6];
    float* out = (float*)d_out;
    jt_mlp_kernel<<<dim3(SEGS * NC_), 256, 0, stream>>>(x, W1, b1, W2, b2, W3, b3, out);
}